// Round 3
// baseline (205.587 us; speedup 1.0000x reference)
//
#include <hip/hip_runtime.h>
#include <hip/hip_bf16.h>

// LSTM cell, B=65536, I=H=128. Inputs/outputs: FLOAT32 (per reference source).
// gates = [x|h] @ [Wx|Wh]^T (+b) via bf16 MFMA (fp32 accumulate), then
// elementwise LSTM epilogue in fp32.
// Tile: 128 batch rows x (4 gates x 32 hidden) = 128x128 outputs, K=256 in
// two 128-halves (x-half then h-half). Gate columns interleaved per wave so
// i/f/g/o for a given (b,j) land in ONE lane's 4 accumulators.
// Staging: fp32 global float4 loads -> in-register cvt to bf16 ->
// ds_write_b128 into XOR-octet-swizzled LDS (conflict-free ds_read_b128).

typedef short s16x8 __attribute__((ext_vector_type(8)));
typedef float f32x4 __attribute__((ext_vector_type(4)));

__device__ __forceinline__ short f2bf(float f) {
    __hip_bfloat16 h = __float2bfloat16(f);
    return __builtin_bit_cast(short, h);
}
__device__ __forceinline__ float sigm(float x) { return 1.0f / (1.0f + __expf(-x)); }
__device__ __forceinline__ float tanh_f(float x) { return 1.0f - 2.0f / (1.0f + __expf(2.0f * x)); }

__global__ __launch_bounds__(256, 2)
void lstm_cell_kernel(const float* __restrict__ X,
                      const float* __restrict__ H,
                      const float* __restrict__ C,
                      const float* __restrict__ Wii, const float* __restrict__ Whi, const float* __restrict__ Bi,
                      const float* __restrict__ Wif, const float* __restrict__ Whf, const float* __restrict__ Bf,
                      const float* __restrict__ Wig, const float* __restrict__ Whg, const float* __restrict__ Bg,
                      const float* __restrict__ Wio, const float* __restrict__ Who, const float* __restrict__ Bo,
                      float* __restrict__ OutH,
                      float* __restrict__ OutC)
{
    // sA[m][oct]: row m (0..127), 16 octets (8 bf16 = 16B); octet stored at
    // index (src_oct ^ (m&15)). sB likewise per gate-column.
    __shared__ short sA[128 * 128];
    __shared__ short sB[128 * 128];

    const int tid = threadIdx.x;
    const int l  = tid & 63;
    const int w  = tid >> 6;
    const int wm = w & 1;    // wave row -> +64*wm batch rows
    const int wn = w >> 1;   // wave col -> +16*wn hidden units
    const int lj = l & 15;   // 0..15
    const int lq = l >> 4;   // 0..3

    const int jt = blockIdx.x & 3;
    const int bb = blockIdx.x >> 2;
    const int B0 = bb * 128;       // batch-row base
    const int J0 = jt * 32;        // hidden-unit base

    f32x4 acc[4][4];               // [m-tile][gate]
#pragma unroll
    for (int mt = 0; mt < 4; ++mt)
#pragma unroll
        for (int g = 0; g < 4; ++g)
            acc[mt][g] = (f32x4){0.f, 0.f, 0.f, 0.f};

#pragma unroll
    for (int half = 0; half < 2; ++half) {
        const float* Asrc = half ? H : X;

        // ---- stage A tile: 2048 chunks; chunk cc = 8 fp32 -> 8 bf16 ----
#pragma unroll
        for (int tt = 0; tt < 2; ++tt) {
            f32x4 f[4][2];
#pragma unroll
            for (int t = 0; t < 4; ++t) {
                const int cc   = (tt * 4 + t) * 256 + tid;
                const int m    = cc >> 4;
                const int oct  = cc & 15;
                const int soct = oct ^ (m & 15);
                const float* src = Asrc + (size_t)(B0 + m) * 128 + soct * 8;
                f[t][0] = *(const f32x4*)src;
                f[t][1] = *(const f32x4*)(src + 4);
            }
#pragma unroll
            for (int t = 0; t < 4; ++t) {
                const int cc = (tt * 4 + t) * 256 + tid;
                s16x8 v;
#pragma unroll
                for (int k = 0; k < 4; ++k) {
                    v[k]     = f2bf(f[t][0][k]);
                    v[4 + k] = f2bf(f[t][1][k]);
                }
                *(s16x8*)(sA + cc * 8) = v;
            }
        }
        // ---- stage B tile: col cl -> gate=(cl>>4)&3, j=J0+16*(cl>>6)+(cl&15) ----
#pragma unroll
        for (int tt = 0; tt < 2; ++tt) {
            f32x4 f[4][2];
#pragma unroll
            for (int t = 0; t < 4; ++t) {
                const int cc   = (tt * 4 + t) * 256 + tid;
                const int cl   = cc >> 4;
                const int oct  = cc & 15;
                const int soct = oct ^ (cl & 15);
                const int gate = (cl >> 4) & 3;
                const int j    = J0 + ((cl >> 6) << 4) + (cl & 15);
                const float* wp;
                if (half == 0)
                    wp = (gate == 0) ? Wii : (gate == 1) ? Wif : (gate == 2) ? Wig : Wio;
                else
                    wp = (gate == 0) ? Whi : (gate == 1) ? Whf : (gate == 2) ? Whg : Who;
                const float* src = wp + (size_t)j * 128 + soct * 8;
                f[t][0] = *(const f32x4*)src;
                f[t][1] = *(const f32x4*)(src + 4);
            }
#pragma unroll
            for (int t = 0; t < 4; ++t) {
                const int cc = (tt * 4 + t) * 256 + tid;
                s16x8 v;
#pragma unroll
                for (int k = 0; k < 4; ++k) {
                    v[k]     = f2bf(f[t][0][k]);
                    v[4 + k] = f2bf(f[t][1][k]);
                }
                *(s16x8*)(sB + cc * 8) = v;
            }
        }
        __syncthreads();

        // ---- MFMA over this 128-k half: 4 k-steps of 32 ----
#pragma unroll
        for (int ks = 0; ks < 4; ++ks) {
            const int oct = (ks * 4 + lq) ^ lj;           // de-swizzle (rows used have row&15==lj)
            s16x8 af[4], bf[4];
#pragma unroll
            for (int mt = 0; mt < 4; ++mt) {
                const int m = wm * 64 + mt * 16 + lj;     // A[m=lane&15][k=quad*8+j]
                af[mt] = *(const s16x8*)(sA + m * 128 + oct * 8);
            }
#pragma unroll
            for (int g = 0; g < 4; ++g) {
                const int cl = wn * 64 + g * 16 + lj;     // W rows = B[k][n] operand, n=lane&15
                bf[g] = *(const s16x8*)(sB + cl * 128 + oct * 8);
            }
#pragma unroll
            for (int mt = 0; mt < 4; ++mt)
#pragma unroll
                for (int g = 0; g < 4; ++g)
                    acc[mt][g] = __builtin_amdgcn_mfma_f32_16x16x32_bf16(
                        af[mt], bf[g], acc[mt][g], 0, 0, 0);
        }
        __syncthreads();
    }

    // ---- epilogue: all 4 gates for (b,j) live in this lane; fp32 I/O ----
    const int j = J0 + wn * 16 + lj;
    const float bi  = Bi[j];
    const float bfv = Bf[j];
    const float bg  = Bg[j];
    const float bo  = Bo[j];

#pragma unroll
    for (int mt = 0; mt < 4; ++mt) {
#pragma unroll
        for (int r = 0; r < 4; ++r) {
            const int b   = B0 + wm * 64 + mt * 16 + lq * 4 + r;  // C/D: row=(lane>>4)*4+reg
            const size_t idx = (size_t)b * 128 + j;
            const float ia = acc[mt][0][r] + bi;
            const float fa = acc[mt][1][r] + bfv;
            const float ga = acc[mt][2][r] + bg;
            const float oa = acc[mt][3][r] + bo;
            const float it = sigm(ia);
            const float ft = sigm(fa);
            const float gt = tanh_f(ga);
            const float ot = sigm(oa);
            const float co = C[idx];
            const float cn = ft * co + it * gt;
            const float hn = ot * tanh_f(cn);
            OutH[idx] = hn;
            OutC[idx] = cn;
        }
    }
}

extern "C" void kernel_launch(void* const* d_in, const int* in_sizes, int n_in,
                              void* d_out, int out_size, void* d_ws, size_t ws_size,
                              hipStream_t stream) {
    const float* X   = (const float*)d_in[0];
    const float* H   = (const float*)d_in[1];
    const float* C   = (const float*)d_in[2];
    const float* Wii = (const float*)d_in[3];
    const float* Whi = (const float*)d_in[4];
    const float* Bi  = (const float*)d_in[5];
    const float* Wif = (const float*)d_in[6];
    const float* Whf = (const float*)d_in[7];
    const float* Bf  = (const float*)d_in[8];
    const float* Wig = (const float*)d_in[9];
    const float* Whg = (const float*)d_in[10];
    const float* Bg  = (const float*)d_in[11];
    const float* Wio = (const float*)d_in[12];
    const float* Who = (const float*)d_in[13];
    const float* Bo  = (const float*)d_in[14];

    float* OutH = (float*)d_out;
    float* OutC = OutH + (size_t)65536 * 128;

    dim3 grid(2048), block(256);
    hipLaunchKernelGGL(lstm_cell_kernel, grid, block, 0, stream,
                       X, H, C, Wii, Whi, Bi, Wif, Whf, Bf,
                       Wig, Whg, Bg, Wio, Who, Bo, OutH, OutC);
}

// Round 4
// 197.659 us; speedup vs baseline: 1.0401x; 1.0401x over previous
//
#include <hip/hip_runtime.h>
#include <hip/hip_bf16.h>

// LSTM cell, B=65536, I=H=128, fp32 I/O. gates = [x|h] @ [Wx|Wh]^T (+b) via
// bf16 MFMA (fp32 acc), fused elementwise LSTM epilogue.
// R4: weights pre-repacked to bf16 MFMA-fragment order in d_ws by a tiny
// kernel (256 KB, L2-resident). Main kernel stages only A (x|h) in LDS
// (32 KB single buffer) -> 3 blocks/CU instead of 2; B-fragments are direct
// global loads hoisted to overlap A staging. Same XOR-octet swizzle, same
// gate-interleaved epilogue (all 4 gates of (b,j) in one lane).

typedef short s16x8 __attribute__((ext_vector_type(8)));
typedef float f32x4 __attribute__((ext_vector_type(4)));

__device__ __forceinline__ short f2bf(float f) {
    __hip_bfloat16 h = __float2bfloat16(f);
    return __builtin_bit_cast(short, h);
}
__device__ __forceinline__ float sigm(float x) { return 1.0f / (1.0f + __expf(-x)); }
__device__ __forceinline__ float tanh_f(float x) { return 1.0f - 2.0f / (1.0f + __expf(2.0f * x)); }

// ---- kernel 1: repack 8 fp32 weight mats -> bf16 fragment-ordered d_ws ----
// Fragment chunk fi = (((jt*2+wn)*4+g)*2+half)*4+ks  (256 chunks x 1 KB).
// Lane l of chunk holds W[j = jt*32+wn*16+(l&15)][k = (ks*4+(l>>4))*8 .. +8).
__global__ __launch_bounds__(256)
void repack_weights(const float* __restrict__ Wii, const float* __restrict__ Whi,
                    const float* __restrict__ Wif, const float* __restrict__ Whf,
                    const float* __restrict__ Wig, const float* __restrict__ Whg,
                    const float* __restrict__ Wio, const float* __restrict__ Who,
                    short* __restrict__ ws)
{
    const int t     = blockIdx.x * 256 + threadIdx.x;   // 16384 threads
    const int chunk = t >> 6;
    const int l     = t & 63;
    const int ks    = chunk & 3;
    const int half  = (chunk >> 2) & 1;
    const int g     = (chunk >> 3) & 3;
    const int wn    = (chunk >> 5) & 1;
    const int jt    = chunk >> 6;
    const int j     = jt * 32 + wn * 16 + (l & 15);
    const int k0    = (ks * 4 + (l >> 4)) * 8;

    const float* wp;
    if (half == 0) wp = (g == 0) ? Wii : (g == 1) ? Wif : (g == 2) ? Wig : Wio;
    else           wp = (g == 0) ? Whi : (g == 1) ? Whf : (g == 2) ? Whg : Who;

    const float* src = wp + (size_t)j * 128 + k0;
    f32x4 a = *(const f32x4*)src;
    f32x4 b = *(const f32x4*)(src + 4);
    s16x8 v;
#pragma unroll
    for (int k = 0; k < 4; ++k) { v[k] = f2bf(a[k]); v[4 + k] = f2bf(b[k]); }
    *(s16x8*)(ws + (size_t)t * 8) = v;
}

// ---- kernel 2: main fused LSTM ----
__global__ __launch_bounds__(256, 3)
void lstm_cell_kernel(const float* __restrict__ X,
                      const float* __restrict__ H,
                      const float* __restrict__ C,
                      const float* __restrict__ Bi, const float* __restrict__ Bf,
                      const float* __restrict__ Bg, const float* __restrict__ Bo,
                      const short* __restrict__ WS,
                      float* __restrict__ OutH,
                      float* __restrict__ OutC)
{
    __shared__ short sA[128 * 128];   // 32 KB: 128 rows x 16 swizzled octets

    const int tid = threadIdx.x;
    const int l  = tid & 63;
    const int w  = tid >> 6;
    const int wm = w & 1;
    const int wn = w >> 1;
    const int lj = l & 15;
    const int lq = l >> 4;

    const int jt = blockIdx.x & 3;
    const int bb = blockIdx.x >> 2;
    const int B0 = bb * 128;
    const int J0 = jt * 32;

    f32x4 acc[4][4];
#pragma unroll
    for (int mt = 0; mt < 4; ++mt)
#pragma unroll
        for (int g = 0; g < 4; ++g)
            acc[mt][g] = (f32x4){0.f, 0.f, 0.f, 0.f};

    // base of this wave's fragment chunks: fi = (((jt*2+wn)*4+g)*2+half)*4+ks
    const short* wsbase = WS + ((size_t)(jt * 2 + wn) * 32) * 512 + l * 8;

#pragma unroll
    for (int half = 0; half < 2; ++half) {
        const float* Asrc = half ? H : X;

        // hoisted B-fragments for this half (global, L2-resident; overlaps staging)
        s16x8 bfh[4][4];   // [g][ks]
#pragma unroll
        for (int g = 0; g < 4; ++g)
#pragma unroll
            for (int ks = 0; ks < 4; ++ks)
                bfh[g][ks] = *(const s16x8*)(wsbase + (size_t)((g * 2 + half) * 4 + ks) * 512);

        // ---- stage A: 2048 x 16B chunks, fp32 -> bf16, XOR-octet swizzle ----
#pragma unroll
        for (int tt = 0; tt < 2; ++tt) {
            f32x4 f[4][2];
#pragma unroll
            for (int t = 0; t < 4; ++t) {
                const int cc   = (tt * 4 + t) * 256 + tid;
                const int m    = cc >> 4;
                const int oct  = cc & 15;
                const int soct = oct ^ (m & 15);
                const float* src = Asrc + (size_t)(B0 + m) * 128 + soct * 8;
                f[t][0] = *(const f32x4*)src;
                f[t][1] = *(const f32x4*)(src + 4);
            }
#pragma unroll
            for (int t = 0; t < 4; ++t) {
                const int cc = (tt * 4 + t) * 256 + tid;
                s16x8 v;
#pragma unroll
                for (int k = 0; k < 4; ++k) {
                    v[k]     = f2bf(f[t][0][k]);
                    v[4 + k] = f2bf(f[t][1][k]);
                }
                *(s16x8*)(sA + cc * 8) = v;
            }
        }
        __syncthreads();

        // ---- MFMA: 4 k-steps of 32 over this half ----
#pragma unroll
        for (int ks = 0; ks < 4; ++ks) {
            const int oct = (ks * 4 + lq) ^ lj;   // de-swizzle (rows used have m&15==lj)
            s16x8 af[4];
#pragma unroll
            for (int mt = 0; mt < 4; ++mt) {
                const int m = wm * 64 + mt * 16 + lj;
                af[mt] = *(const s16x8*)(sA + m * 128 + oct * 8);
            }
#pragma unroll
            for (int mt = 0; mt < 4; ++mt)
#pragma unroll
                for (int g = 0; g < 4; ++g)
                    acc[mt][g] = __builtin_amdgcn_mfma_f32_16x16x32_bf16(
                        af[mt], bfh[g][ks], acc[mt][g], 0, 0, 0);
        }
        __syncthreads();   // protect sA before restaging (half=0 only matters)
    }

    // ---- epilogue: all 4 gates for (b,j) in this lane; fp32 I/O ----
    const int j = J0 + wn * 16 + lj;
    const float bi  = Bi[j];
    const float bfv = Bf[j];
    const float bg  = Bg[j];
    const float bo  = Bo[j];

#pragma unroll
    for (int mt = 0; mt < 4; ++mt) {
#pragma unroll
        for (int r = 0; r < 4; ++r) {
            const int b   = B0 + wm * 64 + mt * 16 + lq * 4 + r;   // C/D: row=(lane>>4)*4+reg
            const size_t idx = (size_t)b * 128 + j;
            const float ia = acc[mt][0][r] + bi;
            const float fa = acc[mt][1][r] + bfv;
            const float ga = acc[mt][2][r] + bg;
            const float oa = acc[mt][3][r] + bo;
            const float it = sigm(ia);
            const float ft = sigm(fa);
            const float gt = tanh_f(ga);
            const float ot = sigm(oa);
            const float co = C[idx];
            const float cn = ft * co + it * gt;
            const float hn = ot * tanh_f(cn);
            OutH[idx] = hn;
            OutC[idx] = cn;
        }
    }
}

extern "C" void kernel_launch(void* const* d_in, const int* in_sizes, int n_in,
                              void* d_out, int out_size, void* d_ws, size_t ws_size,
                              hipStream_t stream) {
    const float* X   = (const float*)d_in[0];
    const float* H   = (const float*)d_in[1];
    const float* C   = (const float*)d_in[2];
    const float* Wii = (const float*)d_in[3];
    const float* Whi = (const float*)d_in[4];
    const float* Bi  = (const float*)d_in[5];
    const float* Wif = (const float*)d_in[6];
    const float* Whf = (const float*)d_in[7];
    const float* Bf  = (const float*)d_in[8];
    const float* Wig = (const float*)d_in[9];
    const float* Whg = (const float*)d_in[10];
    const float* Bg  = (const float*)d_in[11];
    const float* Wio = (const float*)d_in[12];
    const float* Who = (const float*)d_in[13];
    const float* Bo  = (const float*)d_in[14];

    short* ws = (short*)d_ws;   // 256 KB bf16 fragment-ordered weights

    hipLaunchKernelGGL(repack_weights, dim3(64), dim3(256), 0, stream,
                       Wii, Whi, Wif, Whf, Wig, Whg, Wio, Who, ws);

    float* OutH = (float*)d_out;
    float* OutC = OutH + (size_t)65536 * 128;

    hipLaunchKernelGGL(lstm_cell_kernel, dim3(2048), dim3(256), 0, stream,
                       X, H, C, Bi, Bf, Bg, Bo, ws, OutH, OutC);
}